// Round 1
// baseline (6242.030 us; speedup 1.0000x reference)
//
#include <hip/hip_runtime.h>
#include <hip/hip_fp16.h>

// ---- problem constants ----
#define NU 8192      // unlabeled rows per branch
#define NS 8192      // supports per branch (16384/2)
#define D  512
#define C  1000
// 1/tau * log2(e):  exp(dot/0.1) = exp2(dot * 14.4269504)
#define TAU_INV_LOG2E 14.42695040888963f

// output flat offsets (floats)
#define O_OUT1 49545216ull
#define O_OUT2 57737216ull

typedef __attribute__((ext_vector_type(8))) _Float16 half8;
typedef __attribute__((ext_vector_type(4))) float floatx4;

// ---------------- row L2-normalize + f32->f16 ----------------
// rows 0..8191: anchor -> q1 ; 8192..16383: positive -> q2 ; 16384..32767: lb_feat -> kh
__global__ __launch_bounds__(256) void normalize_rows(
    const float* __restrict__ anchor, const float* __restrict__ positive,
    const float* __restrict__ lbf, __half* __restrict__ q1,
    __half* __restrict__ q2, __half* __restrict__ kh) {
  int row = blockIdx.x;
  const float* src; __half* dst; int r;
  if (row < 8192)       { src = anchor;   dst = q1; r = row; }
  else if (row < 16384) { src = positive; dst = q2; r = row - 8192; }
  else                  { src = lbf;      dst = kh; r = row - 16384; }
  int t = threadIdx.x;
  float2 v = ((const float2*)(src + (size_t)r * D))[t];  // 2 cols/thread
  float ss = v.x * v.x + v.y * v.y;
  #pragma unroll
  for (int o = 1; o < 64; o <<= 1) ss += __shfl_xor(ss, o);
  __shared__ float red[4];
  if ((t & 63) == 0) red[t >> 6] = ss;
  __syncthreads();
  float rs = rsqrtf(red[0] + red[1] + red[2] + red[3]);
  ((__half2*)(dst + (size_t)r * D))[t] = __floats2half2_rn(v.x * rs, v.y * rs);
}

// ---------------- one-hot -> label index ----------------
__global__ __launch_bounds__(256) void find_labels(const float* __restrict__ oh,
                                                   int* __restrict__ labels) {
  int row = blockIdx.x;
  const float* p = oh + (size_t)row * C;
  for (int c = threadIdx.x; c < C; c += 256)
    if (p[c] > 0.5f) labels[row] = c;
}

// ---------------- main fused kernel ----------------
// grid: (64 q-tiles, 8 s-chunks, 2 branches), block 256 (4 waves as 2x2 over 128x128)
// Computes exp(QK^T/tau), scatters into num (= d_out region) via atomicAdd,
// accumulates per-row denominators via atomicAdd into den.
__global__ __launch_bounds__(256) void paws_main(
    const __half* __restrict__ q1, const __half* __restrict__ q2,
    const __half* __restrict__ kh, const int* __restrict__ labels,
    float* __restrict__ out, float* __restrict__ den) {
  int b = blockIdx.z;
  const __half* q  = b ? q2 : q1;
  const __half* kb = kh + (size_t)b * NS * D;
  const int* lab   = labels + b * NS;
  float* num  = out + (b ? O_OUT2 : O_OUT1);
  float* denb = den + b * NU;

  // +8 halves pad (16B) -> row stride 144B = 36 words: uniform bank spread, 16B-aligned
  __shared__ __half Qs[128][72];
  __shared__ __half Ks[128][72];

  int tid  = threadIdx.x;
  int wave = tid >> 6, lane = tid & 63;
  int wr = wave >> 1, wc = wave & 1;   // 2x2 wave grid, each wave 64x64
  int l15 = lane & 15, l4 = lane >> 4;
  int qrow0 = blockIdx.x * 128;

  floatx4 acc[4][4];
  float dacc[4][4];  // per-lane denominator partials [rowtile][reg]
  #pragma unroll
  for (int i = 0; i < 4; ++i)
    #pragma unroll
    for (int r = 0; r < 4; ++r) dacc[i][r] = 0.f;

  int srow = tid >> 1;         // staging: 2 threads/row, 64B each
  int sseg = (tid & 1) * 32;   // halves

  for (int st = 0; st < 8; ++st) {
    int s0 = (blockIdx.y * 8 + st) * 128;
    #pragma unroll
    for (int i = 0; i < 4; ++i)
      #pragma unroll
      for (int j = 0; j < 4; ++j) acc[i][j] = (floatx4)0.f;

    for (int kc = 0; kc < 8; ++kc) {  // K chunks of 64
      const uint4* gq = (const uint4*)(q  + (size_t)(qrow0 + srow) * D + kc * 64 + sseg);
      const uint4* gk = (const uint4*)(kb + (size_t)(s0    + srow) * D + kc * 64 + sseg);
      uint4* dq = (uint4*)(&Qs[srow][sseg]);
      uint4* dk = (uint4*)(&Ks[srow][sseg]);
      #pragma unroll
      for (int j = 0; j < 4; ++j) dq[j] = gq[j];
      #pragma unroll
      for (int j = 0; j < 4; ++j) dk[j] = gk[j];
      __syncthreads();
      #pragma unroll
      for (int ks = 0; ks < 2; ++ks) {
        half8 af[4], bf_[4];
        int ko = ks * 32 + l4 * 8;
        #pragma unroll
        for (int i = 0; i < 4; ++i)
          af[i]  = *(const half8*)&Qs[wr * 64 + i * 16 + l15][ko];
        #pragma unroll
        for (int j = 0; j < 4; ++j)
          bf_[j] = *(const half8*)&Ks[wc * 64 + j * 16 + l15][ko];
        #pragma unroll
        for (int i = 0; i < 4; ++i)
          #pragma unroll
          for (int j = 0; j < 4; ++j)
            acc[i][j] = __builtin_amdgcn_mfma_f32_16x16x32_f16(af[i], bf_[j], acc[i][j], 0, 0, 0);
      }
      __syncthreads();
    }

    // epilogue: exp + scatter. C/D layout: col = lane&15, row = (lane>>4)*4 + reg
    int labv[4];
    #pragma unroll
    for (int j = 0; j < 4; ++j) labv[j] = lab[s0 + wc * 64 + j * 16 + l15];
    #pragma unroll
    for (int i = 0; i < 4; ++i) {
      int rbase = qrow0 + wr * 64 + i * 16 + l4 * 4;
      #pragma unroll
      for (int j = 0; j < 4; ++j) {
        #pragma unroll
        for (int r = 0; r < 4; ++r) {
          float e = exp2f(acc[i][j][r] * TAU_INV_LOG2E);
          dacc[i][r] += e;
          atomicAdd(&num[(size_t)(rbase + r) * C + labv[j]], e);
        }
      }
    }
  }

  // denominator: reduce across the 16 lanes sharing each row (low 4 lane bits)
  #pragma unroll
  for (int i = 0; i < 4; ++i) {
    #pragma unroll
    for (int r = 0; r < 4; ++r) {
      float v = dacc[i][r];
      v += __shfl_xor(v, 1);
      v += __shfl_xor(v, 2);
      v += __shfl_xor(v, 4);
      v += __shfl_xor(v, 8);
      if (l15 == 0)
        atomicAdd(&denb[qrow0 + wr * 64 + i * 16 + l4 * 4 + r], v);
    }
  }
}

// ---------------- divide by denominator ----------------
__global__ __launch_bounds__(256) void div_kernel(float* __restrict__ out,
                                                  const float* __restrict__ den) {
  int b = blockIdx.y, row = blockIdx.x;
  float inv = 1.0f / den[b * NU + row];
  float* p = out + (b ? O_OUT2 : O_OUT1) + (size_t)row * C;
  for (int c = threadIdx.x; c < C; c += 256) p[c] *= inv;
}

extern "C" void kernel_launch(void* const* d_in, const int* in_sizes, int n_in,
                              void* d_out, int out_size, void* d_ws, size_t ws_size,
                              hipStream_t stream) {
  const float* anchor    = (const float*)d_in[0];
  const float* positive  = (const float*)d_in[1];
  const float* lbf       = (const float*)d_in[2];
  const float* oh        = (const float*)d_in[3];
  const float* logits_lb = (const float*)d_in[4];
  float* out = (float*)d_out;

  char* ws = (char*)d_ws;
  __half* q1  = (__half*)ws;                 //  8,388,608 B
  __half* q2  = (__half*)(ws + 8388608);     //  8,388,608 B
  __half* kh  = (__half*)(ws + 16777216);    // 16,777,216 B
  int* labels = (int*)(ws + 33554432);       //     65,536 B
  float* den  = (float*)(ws + 33619968);     //     65,536 B

  // zero the atomic accumulators (out1+out2 contiguous in d_out)
  hipMemsetAsync(out + O_OUT1, 0, 16384000ull * 4, stream);
  hipMemsetAsync(den, 0, 2ull * NU * 4, stream);

  // pass-through outputs
  hipMemcpyAsync(out + 0,           anchor,    4194304ull * 4, hipMemcpyDeviceToDevice, stream);
  hipMemcpyAsync(out + 4194304ull,  positive,  4194304ull * 4, hipMemcpyDeviceToDevice, stream);
  hipMemcpyAsync(out + 8388608ull,  lbf,       8388608ull * 4, hipMemcpyDeviceToDevice, stream);
  hipMemcpyAsync(out + 16777216ull, oh,       16384000ull * 4, hipMemcpyDeviceToDevice, stream);
  hipMemcpyAsync(out + 33161216ull, logits_lb,16384000ull * 4, hipMemcpyDeviceToDevice, stream);

  normalize_rows<<<32768, 256, 0, stream>>>(anchor, positive, lbf, q1, q2, kh);
  find_labels<<<16384, 256, 0, stream>>>(oh, labels);
  paws_main<<<dim3(64, 8, 2), 256, 0, stream>>>(q1, q2, kh, labels, out, den);
  div_kernel<<<dim3(8192, 2), 256, 0, stream>>>(out, den);
}

// Round 2
// 1043.889 us; speedup vs baseline: 5.9796x; 5.9796x over previous
//
#include <hip/hip_runtime.h>
#include <hip/hip_fp16.h>

// ---- problem constants ----
#define NU 8192
#define NS 8192
#define D  512
#define C  1000
#define TAU_INV_LOG2E 14.42695040888963f

// output flat offsets (floats)
#define O_OUT1 49545216ull
#define O_OUT2 57737216ull

#define QT  64    // q rows per block (exclusive ownership)
#define STW 128   // supports per s-tile
#define DC  64    // D chunk (halves)

typedef __attribute__((ext_vector_type(8))) _Float16 half8;
typedef __attribute__((ext_vector_type(4))) float floatx4;

// ---------------- one-hot -> label + histogram ----------------
__global__ __launch_bounds__(256) void find_labels_hist(
    const float* __restrict__ oh, int* __restrict__ labels, int* __restrict__ hist) {
  int row = blockIdx.x;
  const float* p = oh + (size_t)row * C;
  for (int c = threadIdx.x; c < C; c += 256)
    if (p[c] > 0.5f) { labels[row] = c; atomicAdd(&hist[(row >> 13) * 1024 + c], 1); }
}

// ---------------- exclusive prefix scan (per branch) ----------------
__global__ __launch_bounds__(1024) void scan_kernel(const int* __restrict__ hist,
                                                    int* __restrict__ cursor) {
  __shared__ int s[1024];
  int b = blockIdx.x, t = threadIdx.x;
  int h = hist[b * 1024 + t];
  s[t] = h;
  __syncthreads();
  for (int o = 1; o < 1024; o <<= 1) {
    int v = (t >= o) ? s[t - o] : 0;
    __syncthreads();
    s[t] += v;
    __syncthreads();
  }
  cursor[b * 1024 + t] = s[t] - h;  // exclusive
}

// ---------------- row L2-normalize + f32->f16 (+ sorted scatter for lb) ----------------
__global__ __launch_bounds__(256) void normalize_scatter(
    const float* __restrict__ anchor, const float* __restrict__ positive,
    const float* __restrict__ lbf, const int* __restrict__ labels,
    int* __restrict__ cursor, int* __restrict__ slab,
    __half* __restrict__ q1, __half* __restrict__ q2, __half* __restrict__ kh) {
  int row = blockIdx.x, t = threadIdx.x;
  __shared__ float red[4];
  __shared__ int spos;
  const float* base;
  __half* dst = nullptr;
  if (row < 8192)       { base = anchor   + (size_t)row * D;          dst = q1 + (size_t)row * D; }
  else if (row < 16384) { base = positive + (size_t)(row - 8192) * D; dst = q2 + (size_t)(row - 8192) * D; }
  else {
    int lrow = row - 16384;
    int b = lrow >> 13;
    if (t == 0) {
      int c = labels[lrow];
      int pos = atomicAdd(&cursor[b * 1024 + c], 1);
      slab[b * 8192 + pos] = c;
      spos = pos;
    }
    base = lbf + (size_t)lrow * D;
  }
  float2 v = ((const float2*)base)[t];
  float ss = v.x * v.x + v.y * v.y;
  #pragma unroll
  for (int o = 1; o < 64; o <<= 1) ss += __shfl_xor(ss, o);
  if ((t & 63) == 0) red[t >> 6] = ss;
  __syncthreads();
  float rs = rsqrtf(red[0] + red[1] + red[2] + red[3]);
  if (row >= 16384) {
    int b = (row - 16384) >> 13;
    dst = kh + ((size_t)b * 8192 + spos) * D;
  }
  ((__half2*)dst)[t] = __floats2half2_rn(v.x * rs, v.y * rs);
}

// ---------------- main fused kernel ----------------
// grid (128, 2), block 512 (8 waves, QK^T wave grid 2x4 over 64x128 tile).
// Sorted supports => per-class sums live in a 64-slot ring window in LDS,
// flushed once per (row,class) with plain stores. Zero global atomics.
__global__ __launch_bounds__(512) void paws_main(
    const __half* __restrict__ q1, const __half* __restrict__ q2,
    const __half* __restrict__ kh, const int* __restrict__ slab,
    float* __restrict__ out, float* __restrict__ den) {
  int b = blockIdx.y;
  const __half* q  = b ? q2 : q1;
  const __half* kb = kh + (size_t)b * NS * D;
  const int* lab   = slab + b * NS;
  float* num = out + (b ? O_OUT2 : O_OUT1);

  // LDS: phase A = Qc[64][72] @0 (9216) + Kc[128][72] @9216 (18432) -> 27648
  //      phase B = E[64][136] @0 (17408, overlays Qc+KcLow)
  //      St[64][136] @27648 (17408, persistent, bits cleared per tile)
  //      win[64][65] f32 @45056 (16640, persistent ring accumulator)
  //      denp[8][32] f32 @61696 (1024)           total 62720 B
  __shared__ __align__(16) char lds[62720];
  __half (*Qc)[72]  = (__half(*)[72])lds;
  __half (*Kc)[72]  = (__half(*)[72])(lds + 9216);
  __half (*E)[136]  = (__half(*)[136])lds;
  __half (*St)[136] = (__half(*)[136])(lds + 27648);
  float (*win)[65]  = (float(*)[65])(lds + 45056);
  float (*denp)[32] = (float(*)[32])(lds + 61696);

  int tid = threadIdx.x;
  int w = tid >> 6, lane = tid & 63;
  int l15 = lane & 15, l4 = lane >> 4;
  int wr = w >> 2, wc = w & 3;  // 2x4 wave grid
  int qrow0 = blockIdx.x * QT;

  // zero persistent LDS (win + St)
  for (int i = tid; i < 64 * 65; i += 512) ((float*)win)[i] = 0.f;
  for (int i = tid; i < 4352; i += 512) ((int*)St)[i] = 0;

  float dacc[2][4];
  #pragma unroll
  for (int i = 0; i < 2; ++i)
    #pragma unroll
    for (int r = 0; r < 4; ++r) dacc[i][r] = 0.f;

  int flush_from = 0;
  int myc = -1;  // this thread's St bit (class) from previous tile

  for (int st = 0; st < 64; ++st) {
    int s0 = st * STW;
    __syncthreads();  // prev tile W-adds + W-reads done; init done (st==0)

    // clear previous tile's St bits
    if (myc >= 0 && tid < 128) St[myc & 63][tid] = __half(0.f);

    // flush completed classes [flush_from, c_lo)
    int c_lo = lab[s0];
    if (c_lo > flush_from) {
      for (int r = w; r < 64; r += 8) {
        for (int cb = flush_from; cb < c_lo; cb += 64) {
          int c = cb + lane;
          if (c < c_lo) {
            int slot = c & 63;
            float v = win[r][slot];
            win[r][slot] = 0.f;
            num[(size_t)(qrow0 + r) * C + c] = v;
          }
        }
      }
      flush_from = c_lo;
    }

    // ---- QK^T over D in chunks of 64 ----
    floatx4 acc[2][2];
    #pragma unroll
    for (int i = 0; i < 2; ++i)
      #pragma unroll
      for (int j = 0; j < 2; ++j) acc[i][j] = (floatx4)0.f;

    for (int kc = 0; kc < 8; ++kc) {
      {
        int r = tid >> 3, sg = (tid & 7) * 8;                      // Qc: 16B/thread
        *(uint4*)&Qc[r][sg] = *(const uint4*)(q + (size_t)(qrow0 + r) * D + kc * DC + sg);
        int r2 = tid >> 2, sg2 = (tid & 3) * 16;                   // Kc: 32B/thread
        *(uint4*)&Kc[r2][sg2]     = *(const uint4*)(kb + (size_t)(s0 + r2) * D + kc * DC + sg2);
        *(uint4*)&Kc[r2][sg2 + 8] = *(const uint4*)(kb + (size_t)(s0 + r2) * D + kc * DC + sg2 + 8);
      }
      __syncthreads();
      #pragma unroll
      for (int kk = 0; kk < 2; ++kk) {
        int ko = kk * 32 + l4 * 8;
        half8 af[2], bf[2];
        af[0] = *(const half8*)&Qc[wr * 32 + l15][ko];
        af[1] = *(const half8*)&Qc[wr * 32 + 16 + l15][ko];
        bf[0] = *(const half8*)&Kc[wc * 32 + l15][ko];
        bf[1] = *(const half8*)&Kc[wc * 32 + 16 + l15][ko];
        #pragma unroll
        for (int i = 0; i < 2; ++i)
          #pragma unroll
          for (int j = 0; j < 2; ++j)
            acc[i][j] = __builtin_amdgcn_mfma_f32_16x16x32_f16(af[i], bf[j], acc[i][j], 0, 0, 0);
      }
      __syncthreads();
    }

    // ---- exp -> E (f16, overlays staging), den partials, St bits ----
    #pragma unroll
    for (int i = 0; i < 2; ++i)
      #pragma unroll
      for (int j = 0; j < 2; ++j)
        #pragma unroll
        for (int r = 0; r < 4; ++r) {
          float e = exp2f(acc[i][j][r] * TAU_INV_LOG2E);
          dacc[i][r] += e;
          E[wr * 32 + i * 16 + l4 * 4 + r][wc * 32 + j * 16 + l15] = __float2half(e);
        }
    if (tid < 128) {
      myc = lab[s0 + tid];
      St[myc & 63][tid] = __half(1.f);
    }
    __syncthreads();

    // ---- W = E(64x128) @ St(128x64): per-class tile sums ----
    floatx4 wacc[2];
    wacc[0] = (floatx4)0.f; wacc[1] = (floatx4)0.f;
    #pragma unroll
    for (int kk = 0; kk < 4; ++kk) {
      int ko = kk * 32 + l4 * 8;
      half8 ea0 = *(const half8*)&E[wr * 32 + l15][ko];
      half8 ea1 = *(const half8*)&E[wr * 32 + 16 + l15][ko];
      half8 sb  = *(const half8*)&St[wc * 16 + l15][ko];
      wacc[0] = __builtin_amdgcn_mfma_f32_16x16x32_f16(ea0, sb, wacc[0], 0, 0, 0);
      wacc[1] = __builtin_amdgcn_mfma_f32_16x16x32_f16(ea1, sb, wacc[1], 0, 0, 0);
    }
    // accumulate into ring window; each (row,slot) has a unique owning lane
    #pragma unroll
    for (int i = 0; i < 2; ++i)
      #pragma unroll
      for (int r = 0; r < 4; ++r)
        win[wr * 32 + i * 16 + l4 * 4 + r][wc * 16 + l15] += wacc[i][r];
  }

  // ---- final flush [flush_from, C) ----
  __syncthreads();
  for (int r = w; r < 64; r += 8) {
    for (int cb = flush_from; cb < C; cb += 64) {
      int c = cb + lane;
      if (c < C) {
        int slot = c & 63;
        float v = win[r][slot];
        win[r][slot] = 0.f;
        num[(size_t)(qrow0 + r) * C + c] = v;
      }
    }
  }

  // ---- denominators (plain stores, rows exclusive) ----
  #pragma unroll
  for (int i = 0; i < 2; ++i)
    #pragma unroll
    for (int r = 0; r < 4; ++r) {
      float v = dacc[i][r];
      v += __shfl_xor(v, 1);
      v += __shfl_xor(v, 2);
      v += __shfl_xor(v, 4);
      v += __shfl_xor(v, 8);
      if (l15 == 0) denp[w][i * 16 + l4 * 4 + r] = v;
    }
  __syncthreads();
  if (tid < 64) {
    int wrr = tid >> 5, rl = tid & 31;
    float s = denp[wrr * 4 + 0][rl] + denp[wrr * 4 + 1][rl] +
              denp[wrr * 4 + 2][rl] + denp[wrr * 4 + 3][rl];
    den[b * NU + qrow0 + tid] = s;
  }
}

// ---------------- divide by denominator ----------------
__global__ __launch_bounds__(256) void div_kernel(float* __restrict__ out,
                                                  const float* __restrict__ den) {
  int b = blockIdx.y, row = blockIdx.x;
  float inv = 1.0f / den[b * NU + row];
  float* p = out + (b ? O_OUT2 : O_OUT1) + (size_t)row * C;
  for (int c = threadIdx.x; c < C; c += 256) p[c] *= inv;
}

extern "C" void kernel_launch(void* const* d_in, const int* in_sizes, int n_in,
                              void* d_out, int out_size, void* d_ws, size_t ws_size,
                              hipStream_t stream) {
  const float* anchor    = (const float*)d_in[0];
  const float* positive  = (const float*)d_in[1];
  const float* lbf       = (const float*)d_in[2];
  const float* oh        = (const float*)d_in[3];
  const float* logits_lb = (const float*)d_in[4];
  float* out = (float*)d_out;

  char* ws = (char*)d_ws;
  __half* q1  = (__half*)ws;                   //  8 MB
  __half* q2  = (__half*)(ws + 8388608);       //  8 MB
  __half* kh  = (__half*)(ws + 16777216);      // 16 MB (sorted-by-label, per branch)
  int* labels = (int*)(ws + 33554432);         // 64 KB
  int* slab   = (int*)(ws + 33619968);         // 64 KB (sorted labels)
  int* hist   = (int*)(ws + 33685504);         //  8 KB
  int* cursor = (int*)(ws + 33693696);         //  8 KB
  float* den  = (float*)(ws + 33701888);       // 64 KB

  hipMemsetAsync(hist, 0, 8192, stream);

  // pass-through outputs
  hipMemcpyAsync(out + 0,           anchor,     4194304ull * 4, hipMemcpyDeviceToDevice, stream);
  hipMemcpyAsync(out + 4194304ull,  positive,   4194304ull * 4, hipMemcpyDeviceToDevice, stream);
  hipMemcpyAsync(out + 8388608ull,  lbf,        8388608ull * 4, hipMemcpyDeviceToDevice, stream);
  hipMemcpyAsync(out + 16777216ull, oh,        16384000ull * 4, hipMemcpyDeviceToDevice, stream);
  hipMemcpyAsync(out + 33161216ull, logits_lb, 16384000ull * 4, hipMemcpyDeviceToDevice, stream);

  find_labels_hist<<<16384, 256, 0, stream>>>(oh, labels, hist);
  scan_kernel<<<2, 1024, 0, stream>>>(hist, cursor);
  normalize_scatter<<<32768, 256, 0, stream>>>(anchor, positive, lbf, labels, cursor,
                                               slab, q1, q2, kh);
  paws_main<<<dim3(128, 2), 512, 0, stream>>>(q1, q2, kh, slab, out, den);
  div_kernel<<<dim3(8192, 2), 256, 0, stream>>>(out, den);
}

// Round 3
// 740.217 us; speedup vs baseline: 8.4327x; 1.4102x over previous
//
#include <hip/hip_runtime.h>
#include <hip/hip_fp16.h>

// ---- problem constants ----
#define NU 8192
#define NS 8192
#define D  512
#define C  1000
#define TAU_INV_LOG2E 14.42695040888963f

// output flat offsets (floats)
#define O_OUT1 49545216ull
#define O_OUT2 57737216ull

typedef __attribute__((ext_vector_type(8))) _Float16 half8;
typedef __attribute__((ext_vector_type(4))) float floatx4;

#define MFMA16(a, b, c) __builtin_amdgcn_mfma_f32_16x16x32_f16(a, b, c, 0, 0, 0)

// ---------------- fused pass-through copy + label extract + histogram ----------------
// float4 grid-stride over all 5 pass-through regions (49,545,216 floats).
// While copying the one-hot region, recover labels[] and per-branch class histogram.
__global__ __launch_bounds__(256) void copy_fused(
    const float4* __restrict__ a, const float4* __restrict__ p,
    const float4* __restrict__ l, const float4* __restrict__ oh,
    const float4* __restrict__ lg, float4* __restrict__ out,
    int* __restrict__ labels, int* __restrict__ hist) {
  size_t stride = (size_t)gridDim.x * 256;
  for (size_t i = (size_t)blockIdx.x * 256 + threadIdx.x; i < 12386304ull; i += stride) {
    float4 v;
    if (i < 1048576)       v = a[i];
    else if (i < 2097152)  v = p[i - 1048576];
    else if (i < 4194304)  v = l[i - 2097152];
    else if (i < 8290304) {
      v = oh[i - 4194304];
      float vv[4] = {v.x, v.y, v.z, v.w};
      #pragma unroll
      for (int j = 0; j < 4; ++j)
        if (vv[j] > 0.5f) {
          int fo = (int)((i - 4194304) * 4) + j;
          int row = fo / 1000, c = fo - row * 1000;
          labels[row] = c;
          atomicAdd(&hist[(row >> 13) * 1024 + c], 1);
        }
    } else                 v = lg[i - 8290304];
    out[i] = v;
  }
}

// ---------------- exclusive prefix scan (per branch) ----------------
__global__ __launch_bounds__(1024) void scan_kernel(const int* __restrict__ hist,
                                                    int* __restrict__ cursor) {
  __shared__ int s[1024];
  int b = blockIdx.x, t = threadIdx.x;
  int h = hist[b * 1024 + t];
  s[t] = h;
  __syncthreads();
  for (int o = 1; o < 1024; o <<= 1) {
    int v = (t >= o) ? s[t - o] : 0;
    __syncthreads();
    s[t] += v;
    __syncthreads();
  }
  cursor[b * 1024 + t] = s[t] - h;  // exclusive
}

// ---------------- row L2-normalize + f32->f16 (+ sorted scatter for lb) ----------------
// one wave per row, 8 rows per 512-thread block
__global__ __launch_bounds__(512) void normalize_rows(
    const float* __restrict__ anchor, const float* __restrict__ positive,
    const float* __restrict__ lbf, const int* __restrict__ labels,
    int* __restrict__ cursor, int* __restrict__ slab,
    __half* __restrict__ q1, __half* __restrict__ q2, __half* __restrict__ kh) {
  int w = threadIdx.x >> 6, lane = threadIdx.x & 63;
  int row = blockIdx.x * 8 + w;
  const float* base;
  __half* dst;
  if (row < 8192)       { base = anchor + (size_t)row * D;            dst = q1 + (size_t)row * D; }
  else if (row < 16384) { base = positive + (size_t)(row - 8192) * D; dst = q2 + (size_t)(row - 8192) * D; }
  else {
    int lrow = row - 16384, br = lrow >> 13;
    base = lbf + (size_t)lrow * D;
    int pos = 0;
    if (lane == 0) {
      int c = labels[lrow];
      pos = atomicAdd(&cursor[br * 1024 + c], 1);
      slab[br * 8192 + pos] = c;
    }
    pos = __shfl(pos, 0);
    dst = kh + ((size_t)br * 8192 + pos) * D;
  }
  float4 x = *(const float4*)(base + lane * 8);
  float4 y = *(const float4*)(base + lane * 8 + 4);
  float ss = x.x * x.x + x.y * x.y + x.z * x.z + x.w * x.w +
             y.x * y.x + y.y * y.y + y.z * y.z + y.w * y.w;
  #pragma unroll
  for (int o = 1; o < 64; o <<= 1) ss += __shfl_xor(ss, o);
  float rs = rsqrtf(ss);
  half8 h;
  h[0] = (_Float16)(x.x * rs); h[1] = (_Float16)(x.y * rs);
  h[2] = (_Float16)(x.z * rs); h[3] = (_Float16)(x.w * rs);
  h[4] = (_Float16)(y.x * rs); h[5] = (_Float16)(y.y * rs);
  h[6] = (_Float16)(y.z * rs); h[7] = (_Float16)(y.w * rs);
  *(half8*)(dst + lane * 8) = h;
}

// ---- async K staging: 128 rows x 256 halves (D-half), XOR-swizzled 16B chunks ----
// LDS_phys[row][ch] = K[s0+row][h*256 + (ch ^ (row&7))*8 ..+8]; rows 512 B contiguous.
__device__ __forceinline__ void stage_half_tile(const __half* __restrict__ kbase,
                                                int s0, int h, char* buf, int w, int lane) {
  int ch = lane & 31, rsel = lane >> 5;
  #pragma unroll
  for (int n = 0; n < 8; ++n) {
    int row = w * 16 + n * 2 + rsel;
    const __half* g = kbase + (size_t)(s0 + row) * D + h * 256 + ((ch ^ (row & 7)) << 3);
    char* ld = buf + (w * 16 + n * 2) * 512;
    __builtin_amdgcn_global_load_lds((const __attribute__((address_space(1))) void*)g,
                                     (__attribute__((address_space(3))) void*)ld, 16, 0, 0);
  }
}

// ---------------- main fused kernel ----------------
// grid (128, 2), 512 threads (8 waves, 2x4 over 64 q-rows x 128 supports).
// Q-resident in VGPRs; K double-buffered via global_load_lds; E/St overlay K0 buffer;
// sorted labels -> 64-slot ring window; final in-place softmax normalization.
__global__ __launch_bounds__(512, 2) void paws_main(
    const __half* __restrict__ q1, const __half* __restrict__ q2,
    const __half* __restrict__ kh, const int* __restrict__ slab,
    float* __restrict__ out) {
  __shared__ __align__(16) char bufA[65536];
  __shared__ __align__(16) char bufB[65536];
  __shared__ float win[64][65];
  __shared__ float denp[8][32];
  __shared__ float den_final[64];

  int b = blockIdx.y;
  const __half* q  = b ? q2 : q1;
  const __half* kb = kh + (size_t)b * NS * D;
  const int* lab   = slab + b * NS;
  float* num = out + (b ? O_OUT2 : O_OUT1);

  int tid = threadIdx.x, w = tid >> 6, lane = tid & 63;
  int l15 = lane & 15, l4 = lane >> 4;
  int wr = w >> 2, wc = w & 3;   // 2x4 wave grid
  int qrow0 = blockIdx.x * 64;
  int swz = l15 & 7;

  // ---- Q-resident A fragments: 2 row-tiles x 16 k-chunks = 128 VGPRs ----
  half8 af[2][16];
  #pragma unroll
  for (int i = 0; i < 2; ++i)
    #pragma unroll
    for (int kc = 0; kc < 16; ++kc)
      af[i][kc] = *(const half8*)(q + (size_t)(qrow0 + wr * 32 + i * 16 + l15) * D + kc * 32 + l4 * 8);

  for (int i = tid; i < 64 * 65; i += 512) ((float*)win)[i] = 0.f;

  // prime: K0(t=0) -> bufA
  stage_half_tile(kb, 0, 0, bufA, w, lane);
  __syncthreads();  // win init visible + K0 drained

  float dacc[2][4];
  #pragma unroll
  for (int i = 0; i < 2; ++i)
    #pragma unroll
    for (int r = 0; r < 4; ++r) dacc[i][r] = 0.f;
  int flush_from = 0;

  for (int t = 0; t < 64; ++t) {
    int s0 = t * 128;
    char* X = (t & 1) ? bufB : bufA;  // holds K0(t) (prefetched)
    char* Y = (t & 1) ? bufA : bufB;  // free (held E/St(t-1))
    __half* Ep  = (__half*)X;
    __half* Stp = (__half*)(X + 18432);

    // issue K1(t) -> Y (overlaps flush + kc0..7)
    stage_half_tile(kb, s0, 1, Y, w, lane);

    // flush completed classes [flush_from, c_lo)
    int c_lo = lab[s0];
    if (c_lo > flush_from) {
      for (int r = w; r < 64; r += 8) {
        float* rowp = num + (size_t)(qrow0 + r) * C;
        for (int c = flush_from + lane; c < c_lo; c += 64) {
          int slot = c & 63;
          rowp[c] = win[r][slot];
          win[r][slot] = 0.f;
        }
      }
      flush_from = c_lo;
    }

    // ---- QK^T: kc 0..7 on X (K0) ----
    floatx4 acc[2][2];
    #pragma unroll
    for (int i = 0; i < 2; ++i)
      #pragma unroll
      for (int j = 0; j < 2; ++j) acc[i][j] = (floatx4)0.f;

    #pragma unroll
    for (int kcl = 0; kcl < 8; ++kcl) {
      int chx = (((kcl * 4 + l4) ^ swz) << 4);
      const char* r0 = X + (size_t)(wc * 32 + l15) * 512 + chx;
      half8 bf0 = *(const half8*)r0;
      half8 bf1 = *(const half8*)(r0 + 16 * 512);
      acc[0][0] = MFMA16(af[0][kcl], bf0, acc[0][0]);
      acc[1][0] = MFMA16(af[1][kcl], bf0, acc[1][0]);
      acc[0][1] = MFMA16(af[0][kcl], bf1, acc[0][1]);
      acc[1][1] = MFMA16(af[1][kcl], bf1, acc[1][1]);
    }
    __syncthreads();  // #1: drains K1(t); X k-reads done

    // St zero (cols 0..127) — X's K0 consumed; overlaps kc8..15
    {
      __half* z = Stp + (tid >> 3) * 144 + (tid & 7) * 16;
      *(uint4*)z = (uint4){0, 0, 0, 0};
      *(uint4*)(z + 8) = (uint4){0, 0, 0, 0};
    }

    // ---- QK^T: kc 8..15 on Y (K1) ----
    #pragma unroll
    for (int kcl = 0; kcl < 8; ++kcl) {
      int chx = (((kcl * 4 + l4) ^ swz) << 4);
      const char* r0 = Y + (size_t)(wc * 32 + l15) * 512 + chx;
      half8 bf0 = *(const half8*)r0;
      half8 bf1 = *(const half8*)(r0 + 16 * 512);
      acc[0][0] = MFMA16(af[0][8 + kcl], bf0, acc[0][0]);
      acc[1][0] = MFMA16(af[1][8 + kcl], bf0, acc[1][0]);
      acc[0][1] = MFMA16(af[0][8 + kcl], bf1, acc[0][1]);
      acc[1][1] = MFMA16(af[1][8 + kcl], bf1, acc[1][1]);
    }
    __syncthreads();  // #2: St zeros complete; Y k-reads done

    // ---- exp -> E (f16, C-layout transposed into A-layout via LDS), St set ----
    #pragma unroll
    for (int i = 0; i < 2; ++i)
      #pragma unroll
      for (int j = 0; j < 2; ++j)
        #pragma unroll
        for (int r = 0; r < 4; ++r) {
          float e = exp2f(acc[i][j][r] * TAU_INV_LOG2E);
          dacc[i][r] += e;
          Ep[(size_t)(wr * 32 + i * 16 + l4 * 4 + r) * 144 + (wc * 32 + j * 16 + l15)] = __float2half(e);
        }
    if (tid < 128) Stp[(size_t)(lab[s0 + tid] & 63) * 144 + tid] = __float2half(1.f);
    __syncthreads();  // #3: E/St ready

    // prefetch K0(t+1) -> Y (overlaps W-phase; Y's reads drained at #2)
    if (t < 63) stage_half_tile(kb, s0 + 128, 0, Y, w, lane);

    // ---- W = E(64x128) @ St(128x64): per-class tile sums -> ring window ----
    floatx4 wacc0 = (floatx4)0.f, wacc1 = (floatx4)0.f;
    #pragma unroll
    for (int kk = 0; kk < 4; ++kk) {
      half8 ea0 = *(const half8*)(Ep + (size_t)(wr * 32 + l15) * 144 + kk * 32 + l4 * 8);
      half8 ea1 = *(const half8*)(Ep + (size_t)(wr * 32 + 16 + l15) * 144 + kk * 32 + l4 * 8);
      half8 sb  = *(const half8*)(Stp + (size_t)(wc * 16 + l15) * 144 + kk * 32 + l4 * 8);
      wacc0 = MFMA16(ea0, sb, wacc0);
      wacc1 = MFMA16(ea1, sb, wacc1);
    }
    #pragma unroll
    for (int r = 0; r < 4; ++r) {
      win[wr * 32 + l4 * 4 + r][wc * 16 + l15] += wacc0[r];
      win[wr * 32 + 16 + l4 * 4 + r][wc * 16 + l15] += wacc1[r];
    }
    __syncthreads();  // #4: win updates done; X free; K0(t+1) drained
  }

  // ---- final flush [flush_from, C) ----
  for (int r = w; r < 64; r += 8) {
    float* rowp = num + (size_t)(qrow0 + r) * C;
    for (int c = flush_from + lane; c < C; c += 64) {
      rowp[c] = win[r][c & 63];
    }
  }

  // ---- denominators -> LDS ----
  #pragma unroll
  for (int i = 0; i < 2; ++i)
    #pragma unroll
    for (int r = 0; r < 4; ++r) {
      float v = dacc[i][r];
      v += __shfl_xor(v, 1);
      v += __shfl_xor(v, 2);
      v += __shfl_xor(v, 4);
      v += __shfl_xor(v, 8);
      if (l15 == 0) denp[w][i * 16 + l4 * 4 + r] = v;
    }
  __syncthreads();
  if (tid < 64) {
    int wr2 = tid >> 5, rl = tid & 31;
    den_final[tid] = denp[wr2 * 4 + 0][rl] + denp[wr2 * 4 + 1][rl] +
                     denp[wr2 * 4 + 2][rl] + denp[wr2 * 4 + 3][rl];
  }
  __syncthreads();

  // ---- in-place softmax normalization of owned rows ----
  for (int r = w; r < 64; r += 8) {
    float inv = 1.0f / den_final[r];
    float* rowp = num + (size_t)(qrow0 + r) * C;
    for (int c = lane; c < C; c += 64) rowp[c] *= inv;
  }
}

extern "C" void kernel_launch(void* const* d_in, const int* in_sizes, int n_in,
                              void* d_out, int out_size, void* d_ws, size_t ws_size,
                              hipStream_t stream) {
  const float* anchor    = (const float*)d_in[0];
  const float* positive  = (const float*)d_in[1];
  const float* lbf       = (const float*)d_in[2];
  const float* oh        = (const float*)d_in[3];
  const float* logits_lb = (const float*)d_in[4];
  float* out = (float*)d_out;

  char* ws = (char*)d_ws;
  __half* q1  = (__half*)ws;                   //  8 MB
  __half* q2  = (__half*)(ws + 8388608);       //  8 MB
  __half* kh  = (__half*)(ws + 16777216);      // 16 MB (sorted-by-label, per branch)
  int* labels = (int*)(ws + 33554432);         // 64 KB
  int* slab   = (int*)(ws + 33619968);         // 64 KB (sorted labels)
  int* hist   = (int*)(ws + 33685504);         //  8 KB
  int* cursor = (int*)(ws + 33693696);         //  8 KB

  hipMemsetAsync(hist, 0, 8192, stream);

  copy_fused<<<4096, 256, 0, stream>>>(
      (const float4*)anchor, (const float4*)positive, (const float4*)lbf,
      (const float4*)oh, (const float4*)logits_lb, (float4*)out, labels, hist);
  scan_kernel<<<2, 1024, 0, stream>>>(hist, cursor);
  normalize_rows<<<4096, 512, 0, stream>>>(anchor, positive, lbf, labels, cursor,
                                           slab, q1, q2, kh);
  paws_main<<<dim3(128, 2), 512, 0, stream>>>(q1, q2, kh, slab, out);
}